// Round 6
// baseline (703.192 us; speedup 1.0000x reference)
//
#include <hip/hip_runtime.h>

#define L  50000     // learners (GEMM M)
#define S  2000      // scenes   (GEMM K)
#define SP 2048      // K padded (table zero-filled past S)
#define D  128       // embed    (GEMM N)
#define HID 16
#define BM 64        // rows per block
#define BK 64        // K chunk per iteration
#define KITERS 32    // 31 full + 1 tail (16 valid k, zero-padded)

typedef _Float16 f16;
typedef _Float16 half8  __attribute__((ext_vector_type(8)));
typedef float    floatx4 __attribute__((ext_vector_type(4)));

// Kernel 1: Bt[d][j] = mlp_out[j][d] in f16, d-major [128][2048], j>=2000 -> 0.
// b2 is folded in, so mask @ Bt^T = mask @ (h W2) + count*b2 directly.
__global__ __launch_bounds__(256) void table_kernel(
    const float* __restrict__ W1, const float* __restrict__ b1,
    const float* __restrict__ W2, const float* __restrict__ b2,
    f16* __restrict__ Bt)
{
    int t = blockIdx.x * 256 + threadIdx.x;    // [0, 128*2048)
    int d = t >> 11;
    int j = t & 2047;
    float acc = b2[d];
    float x = (float)j;
#pragma unroll
    for (int k = 0; k < HID; ++k) {
        float h = fmaxf(fmaf(x, W1[k], b1[k]), 0.0f);
        acc = fmaf(h, W2[k * D + d], acc);
    }
    Bt[t] = (j < S) ? (f16)acc : (f16)0.0f;
}

// Kernel 2: dense MFMA GEMM, A = (M != 0) as f16 1.0/0.0 generated during
// staging, B = Bt (L2-resident). Counts from staging compares (per-thread
// popcount -> 16-lane shfl reduce -> LDS). out = acc / max(count,1).
// Tile: 64 rows x 128 cols per block (4 waves, 16 rows x 8 mfma-tiles each).
__global__ __launch_bounds__(256) void gemm_mask_kernel(
    const float* __restrict__ M, const f16* __restrict__ Bt,
    float* __restrict__ out)
{
    __shared__ f16  As[BM][72];     // 9216 B  (pad 72: row stride 144B, 16B-aligned)
    __shared__ f16  Bs[D][72];      // 18432 B
    __shared__ float cnt_s[BM];

    const int tid  = threadIdx.x;
    const int wave = tid >> 6;
    const int lane = tid & 63;
    const long r0  = (long)blockIdx.x * BM;

    // A staging map: pass p covers rows p*16..p*16+15; thread -> row p*16+(tid>>4),
    // float4 at k = (tid&15)*4. 16 threads/row = 256B contiguous global reads.
    const int arow = tid >> 4;
    const int acol = (tid & 15) * 4;
    // B staging map: thread -> d = tid>>1, 32 halfs at k-offset (tid&1)*32.
    const int bd   = tid >> 1;
    const int bko  = (tid & 1) * 32;

    int cnt4[4] = {0, 0, 0, 0};
    floatx4 acc[8];
#pragma unroll
    for (int n = 0; n < 8; ++n) acc[n] = (floatx4){0.f, 0.f, 0.f, 0.f};

    // ---- prefetch iteration 0 into registers ----
    float4 av[4];
    uint4  bv[4];
    {
        const int k0 = 0;
#pragma unroll
        for (int p = 0; p < 4; ++p) {
            long rg = r0 + p * 16 + arow;
            bool ok = (rg < L);                          // k0=0: k always valid
            av[p] = ok ? *(const float4*)(M + rg * S + k0 + acol)
                       : make_float4(0.f, 0.f, 0.f, 0.f);
        }
#pragma unroll
        for (int i = 0; i < 4; ++i)
            bv[i] = *(const uint4*)(Bt + bd * SP + k0 + bko + i * 8);
    }

    for (int it = 0; it < KITERS; ++it) {
        __syncthreads();                     // prev compute done reading LDS

        // ---- stage regs -> LDS (convert A to f16 mask, count nz) ----
#pragma unroll
        for (int p = 0; p < 4; ++p) {
            float4 v = av[p];
            unsigned m0 = (v.x != 0.f) ? 0x3C00u : 0u;
            unsigned m1 = (v.y != 0.f) ? 0x3C00u : 0u;
            unsigned m2 = (v.z != 0.f) ? 0x3C00u : 0u;
            unsigned m3 = (v.w != 0.f) ? 0x3C00u : 0u;
            cnt4[p] += (v.x != 0.f) + (v.y != 0.f) + (v.z != 0.f) + (v.w != 0.f);
            uint2 w;
            w.x = m0 | (m1 << 16);
            w.y = m2 | (m3 << 16);
            *(uint2*)&As[p * 16 + arow][acol] = w;       // ds_write_b64
        }
#pragma unroll
        for (int i = 0; i < 4; ++i)
            *(uint4*)&Bs[bd][bko + i * 8] = bv[i];       // ds_write_b128

        __syncthreads();

        // ---- prefetch next iteration (overlaps with compute below) ----
        if (it + 1 < KITERS) {
            const int k0 = (it + 1) * BK;
#pragma unroll
            for (int p = 0; p < 4; ++p) {
                long rg = r0 + p * 16 + arow;
                bool ok = (rg < L) && (k0 + acol < S);   // tail iter: zero-pad
                av[p] = ok ? *(const float4*)(M + rg * S + k0 + acol)
                           : make_float4(0.f, 0.f, 0.f, 0.f);
            }
#pragma unroll
            for (int i = 0; i < 4; ++i)
                bv[i] = *(const uint4*)(Bt + bd * SP + k0 + bko + i * 8);
        }

        // ---- compute: 2 k-steps of 32, 8 col-tiles per wave ----
#pragma unroll
        for (int ks = 0; ks < 2; ++ks) {
            // A-frag (m89 layout): lane holds A[m=lane&15][k=(lane>>4)*8+j]
            half8 af = *(const half8*)&As[wave * 16 + (lane & 15)]
                                         [(lane >> 4) * 8 + ks * 32];
#pragma unroll
            for (int n = 0; n < 8; ++n) {
                half8 bf = *(const half8*)&Bs[n * 16 + (lane & 15)]
                                             [(lane >> 4) * 8 + ks * 32];
                acc[n] = __builtin_amdgcn_mfma_f32_16x16x32_f16(af, bf, acc[n], 0, 0, 0);
            }
        }
    }

    // ---- counts: reduce each row's 16 k-slice partials (lanes sharing
    // lane>>4 hold the same row p*16 + wave*4 + (lane>>4)) ----
#pragma unroll
    for (int p = 0; p < 4; ++p) {
        int c = cnt4[p];
        c += __shfl_xor(c, 1);
        c += __shfl_xor(c, 2);
        c += __shfl_xor(c, 4);
        c += __shfl_xor(c, 8);
        if ((lane & 15) == 0)
            cnt_s[p * 16 + wave * 4 + (lane >> 4)] = (float)c;
    }
    __syncthreads();                         // cnt_s is cross-wave

    // ---- epilogue: C/D layout row=(lane>>4)*4+reg, col=lane&15 (m89) ----
    float inv[4];
#pragma unroll
    for (int r = 0; r < 4; ++r) {
        float c = cnt_s[wave * 16 + (lane >> 4) * 4 + r];
        inv[r] = 1.0f / fmaxf(c, 1.0f);
    }
#pragma unroll
    for (int n = 0; n < 8; ++n) {
#pragma unroll
        for (int r = 0; r < 4; ++r) {
            long rg = r0 + wave * 16 + (lane >> 4) * 4 + r;
            if (rg < L)
                out[rg * D + n * 16 + (lane & 15)] = acc[n][r] * inv[r];
        }
    }
}

extern "C" void kernel_launch(void* const* d_in, const int* in_sizes, int n_in,
                              void* d_out, int out_size, void* d_ws, size_t ws_size,
                              hipStream_t stream) {
    const float* M  = (const float*)d_in[0];   // [50000, 2000]
    const float* W1 = (const float*)d_in[1];   // [1, 16]
    const float* b1 = (const float*)d_in[2];   // [16]
    const float* W2 = (const float*)d_in[3];   // [16, 128]
    const float* b2 = (const float*)d_in[4];   // [128]
    float* out = (float*)d_out;                // [50000, 128]

    f16* Bt = (f16*)d_ws;                      // 128*2048*2 = 512 KB scratch

    table_kernel<<<(D * SP) / 256, 256, 0, stream>>>(W1, b1, W2, b2, Bt);
    gemm_mask_kernel<<<(L + BM - 1) / BM, 256, 0, stream>>>(M, Bt, out);
}